// Round 2
// baseline (410.160 us; speedup 1.0000x reference)
//
#include <hip/hip_runtime.h>

// Problem constants
#define NH   32      // query heads
#define NKV  8       // kv heads
#define LQ   2048    // query length
#define SK   2048    // key length
#define DH   128     // head dim
#define BM   128     // q rows per block
#define BN   64      // s columns per iteration
#define NT   (SK / BN)   // 32 k-tiles
#define VSTRIDE 72   // prepass transpose LDS stride (shorts)

typedef __attribute__((ext_vector_type(8)))  short bf8;
typedef __attribute__((ext_vector_type(16))) float f16v;
typedef __attribute__((ext_vector_type(4)))  unsigned int u32x4;

#if __has_builtin(__builtin_amdgcn_exp2f)
#define EXP2F(x) __builtin_amdgcn_exp2f(x)
#else
#define EXP2F(x) exp2f(x)
#endif

// fp32 -> bf16 round-to-nearest-even (finite inputs)
__device__ __forceinline__ unsigned short f2bf(float f) {
    unsigned int u = __builtin_bit_cast(unsigned int, f);
    u = (u + 0x7FFFu + ((u >> 16) & 1u)) >> 16;
    return (unsigned short)u;
}

__device__ __forceinline__ unsigned int cvtpk_bf16(float lo, float hi) {
    unsigned int r;
    asm("v_cvt_pk_bf16_f32 %0, %1, %2" : "=v"(r) : "v"(lo), "v"(hi));
    return r;
}

#define GLOAD_LDS16(g, l)                                                      \
    __builtin_amdgcn_global_load_lds(                                          \
        (const __attribute__((address_space(1))) void*)(g),                    \
        (__attribute__((address_space(3))) void*)(l), 16, 0, 0)

// ---------------- pre-pass 1: K fp32 -> bf16, chunk-swizzled rows ----------------
// Kb[kv][s][p] (16B chunks p=0..15) holds source d-chunk c = p ^ (s&15), so a
// LINEAR global->LDS DMA of a 64-row tile yields an XOR-swizzled LDS tile
// (conflict-free column-wise ds_read_b128).
__global__ __launch_bounds__(256) void convert_k_kernel(
    const float* __restrict__ K, unsigned short* __restrict__ Kb)
{
    unsigned int cid = blockIdx.x * 256 + threadIdx.x;   // one 16B chunk per thread
    unsigned int p   = cid & 15;
    unsigned int row = cid >> 4;            // kv*2048 + s
    unsigned int s   = row & (SK - 1);
    unsigned int c   = p ^ (s & 15);
    const float* src = K + (size_t)row * DH + c * 8;
    float4 a = *(const float4*)(src);
    float4 b = *(const float4*)(src + 4);
    bf8 o;
    o[0] = (short)f2bf(a.x); o[1] = (short)f2bf(a.y);
    o[2] = (short)f2bf(a.z); o[3] = (short)f2bf(a.w);
    o[4] = (short)f2bf(b.x); o[5] = (short)f2bf(b.y);
    o[6] = (short)f2bf(b.z); o[7] = (short)f2bf(b.w);
    *(bf8*)(Kb + (size_t)row * DH + p * 8) = o;
}

// ---------------- pre-pass 2: V -> V^T bf16, TILE-blocked + chunk-swizzled ----------------
// VTb layout: [kv][tile t (64 s)][d=0..127][p=0..7] 16B chunks; chunk p of row d
// holds s-chunk c = p ^ (d&7). Each tile is 16KB contiguous -> linear DMA staging.
__global__ __launch_bounds__(256) void transpose_v_kernel(
    const float* __restrict__ V, unsigned short* __restrict__ VTb)
{
    __shared__ __align__(16) unsigned short Vl[DH * VSTRIDE];
    const int tid = threadIdx.x;
    const int kv  = blockIdx.x >> 5;          // 32 s-tiles per kv head
    const int t   = blockIdx.x & 31;
    const int s0  = t * 64;
    const float* Vh = V + (size_t)kv * SK * DH;

    #pragma unroll
    for (int i = 0; i < 8; ++i) {
        int idx = tid * 4 + i * 1024;
        int s = idx >> 7, d = idx & 127;
        const float4 v4 = *(const float4*)(Vh + (size_t)(s0 + s) * DH + d);
        Vl[(d + 0) * VSTRIDE + s] = f2bf(v4.x);
        Vl[(d + 1) * VSTRIDE + s] = f2bf(v4.y);
        Vl[(d + 2) * VSTRIDE + s] = f2bf(v4.z);
        Vl[(d + 3) * VSTRIDE + s] = f2bf(v4.w);
    }
    __syncthreads();
    unsigned short* out = VTb + (size_t)(kv * 32 + t) * (DH * 64);
    #pragma unroll
    for (int i = 0; i < 4; ++i) {
        int c = tid + i * 256;                // 1024 chunks of 8 shorts
        int d = c >> 3, p = c & 7;
        int sc = (p ^ (d & 7)) * 8;
        *(bf8*)(out + d * 64 + p * 8) = *(const bf8*)(Vl + d * VSTRIDE + sc);
    }
}

// ---------------- main fused attention ----------------
// 4 waves = 2 q-groups (64 q) x 2 s-halves (32 s). Per wave:
//   S^T = K*Q^T : 8 aK LDS reads feed 16 MFMA (2 q-tiles)  -> A-frag reuse x2
//   softmax fully in-register; P packed via v_cvt_pk_bf16_f32 + v_permlane32_swap
//   O^T += V^T*P^T over own 32-s half: 8 aV reads feed 16 MFMA; sg pair reduced at end
// Staging: global_load_lds double-buffer, counted vmcnt (never 0 in loop), raw barriers.
__global__ __launch_bounds__(256, 2) void fattn_kernel(
    const float* __restrict__ Q, const unsigned short* __restrict__ Kb,
    const unsigned short* __restrict__ VTb, const float* __restrict__ M,
    float* __restrict__ O)
{
    __shared__ __align__(1024) unsigned char smem[65536];
    unsigned char* KB = smem;               // 2 x 16KB K tiles [s=64][256B swz]
    unsigned char* VB = smem + 32768;       // 2 x 16KB V tiles [d=128][128B swz]

    const int tid  = threadIdx.x;
    const int wave = tid >> 6;
    const int lane = tid & 63;
    const int l32  = lane & 31;
    const int hh   = lane >> 5;
    const int qg   = wave >> 1;             // q-group (64 rows)
    const int sg   = wave & 1;              // s-half (32 cols)

    // XCD swizzle: 64 consecutive logical blocks (= 1 kv head) per XCD
    const int bx = ((int)blockIdx.x & 7) * 64 + ((int)blockIdx.x >> 3);
    const int h  = bx >> 4;
    const int lt = bx & 15;
    const int q0 = lt * BM;
    const int kv = h >> 2;

    const float* Qh = Q + (size_t)h * LQ * DH;
    const unsigned char* Kg = (const unsigned char*)(Kb  + (size_t)kv * SK * DH);
    const unsigned char* Vg = (const unsigned char*)(VTb + (size_t)kv * SK * DH);

    const int qrow0 = q0 + qg * 64 + l32;
    const float* Mq0 = M + (size_t)qrow0 * SK;
    const float* Mq1 = Mq0 + (size_t)32 * SK;

    // ---- Q preload as B-fragments: n=q, k=d = ks*16 + hh*8 + j ----
    bf8 bQ[2][8];
    #pragma unroll
    for (int qt = 0; qt < 2; ++qt) {
        const float* qp = Qh + (size_t)(qrow0 + qt * 32) * DH + hh * 8;
        #pragma unroll
        for (int ks = 0; ks < 8; ++ks) {
            float4 a = *(const float4*)(qp + ks * 16);
            float4 b = *(const float4*)(qp + ks * 16 + 4);
            bf8 o;
            o[0] = (short)f2bf(a.x); o[1] = (short)f2bf(a.y);
            o[2] = (short)f2bf(a.z); o[3] = (short)f2bf(a.w);
            o[4] = (short)f2bf(b.x); o[5] = (short)f2bf(b.y);
            o[6] = (short)f2bf(b.z); o[7] = (short)f2bf(b.w);
            bQ[qt][ks] = o;
        }
    }

    // LDS read byte-offset bases; per-read addr = base ^ (ks<<5) (bits disjoint)
    const int krowz = (sg * 32 + l32) * 256 + ((hh * 16) ^ ((l32 & 15) << 4));
    const int vrowz = l32 * 128 + ((sg * 64 + hh * 16) ^ ((l32 & 7) << 4));

    const int stoff = wave * 4096 + lane * 16;   // staging: 4KB K + 4KB V per wave

    f16v accO[4][2];
    #pragma unroll
    for (int dt = 0; dt < 4; ++dt)
        #pragma unroll
        for (int qt = 0; qt < 2; ++qt)
            #pragma unroll
            for (int r = 0; r < 16; ++r) accO[dt][qt][r] = 0.f;
    float lp0 = 0.f, lp1 = 0.f;
    const float cl2e = 0.08838834764831845f * 1.4426950408889634f;

    // prologue: stage tile 0 into buffer 0
    #pragma unroll
    for (int c = 0; c < 4; ++c) GLOAD_LDS16(Kg + stoff + c * 1024, KB + stoff + c * 1024);
    #pragma unroll
    for (int c = 0; c < 4; ++c) GLOAD_LDS16(Vg + stoff + c * 1024, VB + stoff + c * 1024);

    for (int t = 0; t < NT; ++t) {
        const int cur = t & 1;

        // ---- mask loads for tile t (BEFORE stage issue: their auto-wait stays vmcnt(8)) ----
        const float* mp0 = Mq0 + t * 64 + sg * 32 + hh * 4;
        const float* mp1 = Mq1 + t * 64 + sg * 32 + hh * 4;
        float4 mv0[4], mv1[4];
        #pragma unroll
        for (int g = 0; g < 4; ++g) mv0[g] = *(const float4*)(mp0 + g * 8);
        #pragma unroll
        for (int g = 0; g < 4; ++g) mv1[g] = *(const float4*)(mp1 + g * 8);
        __builtin_amdgcn_sched_barrier(0);

        // ---- stage tile t+1 (wrap on last iter keeps vmcnt bookkeeping uniform) ----
        {
            const int tn = (t + 1) & (NT - 1);
            const unsigned char* ksrc = Kg + (size_t)tn * 16384 + stoff;
            const unsigned char* vsrc = Vg + (size_t)tn * 16384 + stoff;
            unsigned char* kdst = KB + (cur ^ 1) * 16384 + stoff;
            unsigned char* vdst = VB + (cur ^ 1) * 16384 + stoff;
            #pragma unroll
            for (int c = 0; c < 4; ++c) GLOAD_LDS16(ksrc + c * 1024, kdst + c * 1024);
            #pragma unroll
            for (int c = 0; c < 4; ++c) GLOAD_LDS16(vsrc + c * 1024, vdst + c * 1024);
        }
        __builtin_amdgcn_sched_barrier(0);
        // outstanding: stage_t(8) + mask_t(8) + stage_{t+1}(8) -> drain stage_t only
        asm volatile("s_waitcnt vmcnt(16)" ::: "memory");
        __builtin_amdgcn_s_barrier();
        asm volatile("" ::: "memory");

        // ---- S^T = K * Q^T over this wave's 32-s half ----
        const unsigned char* kb = KB + cur * 16384;
        f16v s0, s1;
        #pragma unroll
        for (int r = 0; r < 16; ++r) { s0[r] = 0.f; s1[r] = 0.f; }
        __builtin_amdgcn_s_setprio(1);
        #pragma unroll
        for (int ks = 0; ks < 8; ++ks) {
            bf8 aK = *(const bf8*)(kb + (krowz ^ (ks << 5)));
            s0 = __builtin_amdgcn_mfma_f32_32x32x16_bf16(aK, bQ[0][ks], s0, 0, 0, 0);
            s1 = __builtin_amdgcn_mfma_f32_32x32x16_bf16(aK, bQ[1][ks], s1, 0, 0, 0);
        }
        __builtin_amdgcn_s_setprio(0);

        // ---- softmax (|z| bounded; no running max needed) + in-register P pack ----
        unsigned int pk0[8], pk1[8];
        #pragma unroll
        for (int g = 0; g < 4; ++g) {
            float e0 = EXP2F((s0[g*4+0] + mv0[g].x) * cl2e);
            float e1 = EXP2F((s0[g*4+1] + mv0[g].y) * cl2e);
            float e2 = EXP2F((s0[g*4+2] + mv0[g].z) * cl2e);
            float e3 = EXP2F((s0[g*4+3] + mv0[g].w) * cl2e);
            lp0 += (e0 + e1) + (e2 + e3);
            pk0[g*2+0] = cvtpk_bf16(e0, e1);
            pk0[g*2+1] = cvtpk_bf16(e2, e3);
        }
        #pragma unroll
        for (int g = 0; g < 4; ++g) {
            float e0 = EXP2F((s1[g*4+0] + mv1[g].x) * cl2e);
            float e1 = EXP2F((s1[g*4+1] + mv1[g].y) * cl2e);
            float e2 = EXP2F((s1[g*4+2] + mv1[g].z) * cl2e);
            float e3 = EXP2F((s1[g*4+3] + mv1[g].w) * cl2e);
            lp1 += (e0 + e1) + (e2 + e3);
            pk1[g*2+0] = cvtpk_bf16(e0, e1);
            pk1[g*2+1] = cvtpk_bf16(e2, e3);
        }
        // half-wave exchange via v_permlane32_swap_b32 (VDST[32:63] <-> SRC0[0:31]):
        //   swap(A,B): newA = {A_lo, B_lo}, newB = {A_hi, B_hi}.
        // Fragment word w for lane-half hh, block G=2ks+hh:
        //   w0 = half0's pk[2G], w1 = half0's pk[2G+1], w2 = half1's pk[2G], w3 = half1's pk[2G+1]
        // -> swap(pk[4ks], pk[4ks+2]) gives w0 (newA) and w2 (newB);
        //    swap(pk[4ks+1], pk[4ks+3]) gives w1 (newA) and w3 (newB).
        bf8 bP0[2], bP1[2];
        #pragma unroll
        for (int ks = 0; ks < 2; ++ks) {
            unsigned int a0 = pk0[4*ks+0], b0 = pk0[4*ks+2];
            unsigned int a1 = pk0[4*ks+1], b1 = pk0[4*ks+3];
            asm volatile("v_permlane32_swap_b32 %0, %1" : "+v"(a0), "+v"(b0));
            asm volatile("v_permlane32_swap_b32 %0, %1" : "+v"(a1), "+v"(b1));
            u32x4 w; w[0] = a0; w[1] = a1; w[2] = b0; w[3] = b1;
            bP0[ks] = __builtin_bit_cast(bf8, w);
            unsigned int c0 = pk1[4*ks+0], d0 = pk1[4*ks+2];
            unsigned int c1 = pk1[4*ks+1], d1 = pk1[4*ks+3];
            asm volatile("v_permlane32_swap_b32 %0, %1" : "+v"(c0), "+v"(d0));
            asm volatile("v_permlane32_swap_b32 %0, %1" : "+v"(c1), "+v"(d1));
            u32x4 w2; w2[0] = c0; w2[1] = c1; w2[2] = d0; w2[3] = d1;
            bP1[ks] = __builtin_bit_cast(bf8, w2);
        }

        // ---- O^T += V^T * P^T over this wave's 32-s half (k-split; reduced at end) ----
        const unsigned char* vb = VB + cur * 16384;
        __builtin_amdgcn_s_setprio(1);
        #pragma unroll
        for (int dt = 0; dt < 4; ++dt) {
            #pragma unroll
            for (int ks = 0; ks < 2; ++ks) {
                bf8 aV = *(const bf8*)(vb + dt * 4096 + (vrowz ^ (ks << 5)));
                accO[dt][0] = __builtin_amdgcn_mfma_f32_32x32x16_bf16(aV, bP0[ks], accO[dt][0], 0, 0, 0);
                accO[dt][1] = __builtin_amdgcn_mfma_f32_32x32x16_bf16(aV, bP1[ks], accO[dt][1], 0, 0, 0);
            }
        }
        __builtin_amdgcn_s_setprio(0);
        asm volatile("" ::: "memory");
        __builtin_amdgcn_s_barrier();
        asm volatile("" ::: "memory");
    }

    // ---- epilogue: combine the two s-halves via LDS (2 rounds of 32KB) ----
    asm volatile("s_waitcnt vmcnt(0)" ::: "memory");   // drain wrap-stage before reuse
    __builtin_amdgcn_s_barrier();
    asm volatile("" ::: "memory");
    float* xs  = (float*)smem;              // 32KB per round: [qg][dt][r][lane]
    float* lsc = (float*)(smem + 32768);    // 2KB lpart exchange
    const int pw = qg * 2 + (sg ^ 1);       // partner wave id
    lsc[(wave * 2 + 0) * 64 + lane] = lp0;
    lsc[(wave * 2 + 1) * 64 + lane] = lp1;
    float lq[2];
    float* Op0 = O + (size_t)h * LQ * DH + (size_t)qrow0 * DH;
    #pragma unroll
    for (int qt = 0; qt < 2; ++qt) {
        #pragma unroll
        for (int i = 0; i < 2; ++i) {           // export partner-owned d-tiles
            const int dt = (sg ^ 1) * 2 + i;
            #pragma unroll
            for (int r = 0; r < 16; ++r)
                xs[((qg * 4 + dt) * 16 + r) * 64 + lane] = accO[dt][qt][r];
        }
        asm volatile("" ::: "memory");
        __builtin_amdgcn_s_barrier();
        asm volatile("" ::: "memory");
        if (qt == 0) {
            lq[0] = lp0 + lsc[(pw * 2 + 0) * 64 + lane];
            lq[1] = lp1 + lsc[(pw * 2 + 1) * 64 + lane];
            lq[0] += __shfl_xor(lq[0], 32);
            lq[1] += __shfl_xor(lq[1], 32);
        }
        const float inv = 1.0f / lq[qt];
        float* Op = Op0 + (size_t)qt * 32 * DH;
        #pragma unroll
        for (int i = 0; i < 2; ++i) {           // own d-tiles: add partner partial, store
            const int dt = sg * 2 + i;
            #pragma unroll
            for (int g = 0; g < 4; ++g) {
                float4 o;
                o.x = (accO[dt][qt][g*4+0] + xs[((qg*4+dt)*16 + g*4+0)*64 + lane]) * inv;
                o.y = (accO[dt][qt][g*4+1] + xs[((qg*4+dt)*16 + g*4+1)*64 + lane]) * inv;
                o.z = (accO[dt][qt][g*4+2] + xs[((qg*4+dt)*16 + g*4+2)*64 + lane]) * inv;
                o.w = (accO[dt][qt][g*4+3] + xs[((qg*4+dt)*16 + g*4+3)*64 + lane]) * inv;
                *(float4*)(Op + dt * 32 + g * 8 + hh * 4) = o;
            }
        }
        if (qt == 0) {
            asm volatile("" ::: "memory");
            __builtin_amdgcn_s_barrier();       // protect xs before qt=1 export
            asm volatile("" ::: "memory");
        }
    }
}

extern "C" void kernel_launch(void* const* d_in, const int* in_sizes, int n_in,
                              void* d_out, int out_size, void* d_ws, size_t ws_size,
                              hipStream_t stream) {
    const float* Q = (const float*)d_in[0];   // [1,32,2048,128]
    const float* K = (const float*)d_in[1];   // [1,8,2048,128]
    const float* V = (const float*)d_in[2];   // [1,8,2048,128]
    const float* M = (const float*)d_in[3];   // [1,1,2048,2048]
    float* O = (float*)d_out;

    // workspace: Kb bf16 [8*2048*128] then VTb bf16 [8*128*2048] (tiled layout)
    unsigned short* Kb  = (unsigned short*)d_ws;
    unsigned short* VTb = Kb + (size_t)NKV * SK * DH;

    convert_k_kernel<<<dim3((NKV * SK * 16) / 256), 256, 0, stream>>>(K, Kb);
    transpose_v_kernel<<<dim3(NKV * (SK / 64)), 256, 0, stream>>>(V, VTb);

    dim3 grid(NH * (LQ / BM));                // 512 blocks = 2/CU
    fattn_kernel<<<grid, 256, 0, stream>>>(Q, Kb, VTb, M, O);
}

// Round 4
// 356.345 us; speedup vs baseline: 1.1510x; 1.1510x over previous
//
#include <hip/hip_runtime.h>

// Problem constants
#define NH   32      // query heads
#define NKV  8       // kv heads
#define LQ   2048    // query length
#define SK   2048    // key length
#define DH   128     // head dim
#define BM   128     // q rows per block
#define BN   64      // s columns per iteration
#define NT   (SK / BN)   // 32 k-tiles
#define VSTRIDE 72   // prepass transpose LDS stride (shorts)

typedef __attribute__((ext_vector_type(8)))  short bf8;
typedef __attribute__((ext_vector_type(16))) float f16v;
typedef __attribute__((ext_vector_type(4)))  unsigned int u32x4;

#define CL2E 0.12754308753f   // (1/sqrt(128)) * log2(e)

#if __has_builtin(__builtin_amdgcn_exp2f)
#define EXP2F(x) __builtin_amdgcn_exp2f(x)
#else
#define EXP2F(x) exp2f(x)
#endif

// fp32 -> bf16 round-to-nearest-even (finite inputs)
__device__ __forceinline__ unsigned short f2bf(float f) {
    unsigned int u = __builtin_bit_cast(unsigned int, f);
    u = (u + 0x7FFFu + ((u >> 16) & 1u)) >> 16;
    return (unsigned short)u;
}

__device__ __forceinline__ unsigned int cvtpk_bf16(float lo, float hi) {
    unsigned int r;
    asm("v_cvt_pk_bf16_f32 %0, %1, %2" : "=v"(r) : "v"(lo), "v"(hi));
    return r;
}

__device__ __forceinline__ float bflo(unsigned int u) {
    return __builtin_bit_cast(float, u << 16);
}
__device__ __forceinline__ float bfhi(unsigned int u) {
    return __builtin_bit_cast(float, u & 0xFFFF0000u);
}

// offset argument must be a LITERAL 0 (semantic check precedes unrolling);
// fold all offsets into the two pointers instead.
#define GLOAD_LDS16(g, l)                                                      \
    __builtin_amdgcn_global_load_lds(                                          \
        (const __attribute__((address_space(1))) void*)(g),                    \
        (__attribute__((address_space(3))) void*)(l), 16, 0, 0)

// ---------------- pre-pass 1: K fp32 -> bf16, chunk-swizzled rows ----------------
// Kb[kv][s][p] (16B chunks p=0..15) holds source d-chunk c = p ^ (s&15): linear
// global->LDS DMA of a 64-row tile yields an XOR-swizzled LDS tile.
__global__ __launch_bounds__(256) void convert_k_kernel(
    const float* __restrict__ K, unsigned short* __restrict__ Kb)
{
    unsigned int cid = blockIdx.x * 256 + threadIdx.x;   // one 16B chunk per thread
    unsigned int p   = cid & 15;
    unsigned int row = cid >> 4;            // kv*2048 + s
    unsigned int s   = row & (SK - 1);
    unsigned int c   = p ^ (s & 15);
    const float* src = K + (size_t)row * DH + c * 8;
    float4 a = *(const float4*)(src);
    float4 b = *(const float4*)(src + 4);
    bf8 o;
    o[0] = (short)f2bf(a.x); o[1] = (short)f2bf(a.y);
    o[2] = (short)f2bf(a.z); o[3] = (short)f2bf(a.w);
    o[4] = (short)f2bf(b.x); o[5] = (short)f2bf(b.y);
    o[6] = (short)f2bf(b.z); o[7] = (short)f2bf(b.w);
    *(bf8*)(Kb + (size_t)row * DH + p * 8) = o;
}

// ---------------- pre-pass 2: V -> V^T bf16, TILE-blocked + chunk-swizzled ----------------
// VTb layout: [kv][tile t (64 s)][d=0..127][p=0..7] 16B chunks; chunk p of row d
// holds s-chunk c = p ^ (d&7). Each tile is 16KB contiguous -> linear DMA staging.
__global__ __launch_bounds__(256) void transpose_v_kernel(
    const float* __restrict__ V, unsigned short* __restrict__ VTb)
{
    __shared__ __align__(16) unsigned short Vl[DH * VSTRIDE];
    const int tid = threadIdx.x;
    const int kv  = blockIdx.x >> 5;          // 32 s-tiles per kv head
    const int t   = blockIdx.x & 31;
    const int s0  = t * 64;
    const float* Vh = V + (size_t)kv * SK * DH;

    #pragma unroll
    for (int i = 0; i < 8; ++i) {
        int idx = tid * 4 + i * 1024;
        int s = idx >> 7, d = idx & 127;
        const float4 v4 = *(const float4*)(Vh + (size_t)(s0 + s) * DH + d);
        Vl[(d + 0) * VSTRIDE + s] = f2bf(v4.x);
        Vl[(d + 1) * VSTRIDE + s] = f2bf(v4.y);
        Vl[(d + 2) * VSTRIDE + s] = f2bf(v4.z);
        Vl[(d + 3) * VSTRIDE + s] = f2bf(v4.w);
    }
    __syncthreads();
    unsigned short* out = VTb + (size_t)(kv * 32 + t) * (DH * 64);
    #pragma unroll
    for (int i = 0; i < 4; ++i) {
        int c = tid + i * 256;                // 1024 chunks of 8 shorts
        int d = c >> 3, p = c & 7;
        int sc = (p ^ (d & 7)) * 8;
        *(bf8*)(out + d * 64 + p * 8) = *(const bf8*)(Vl + d * VSTRIDE + sc);
    }
}

// ---------------- pre-pass 3: mask fp32 -> bf16, pre-scaled by scale*log2e ----------------
// Column-permuted within each 64-col tile so each lane's 16 values per q-tile are
// two contiguous b128 loads: local c' = sg*32 + hh*16 + g*4 + j holds source
// col sg*32 + g*8 + hh*4 + j  (matches 32x32 MFMA D-layout row = j + 8g + 4hh).
__global__ __launch_bounds__(256) void convert_m_kernel(
    const float* __restrict__ M, unsigned short* __restrict__ Mb)
{
    unsigned int cid = blockIdx.x * 256 + threadIdx.x;   // one 8-short output chunk
    unsigned int row = cid >> 8;                         // 256 chunks per row
    unsigned int l   = (cid & 255) * 8;                  // permuted col index
    unsigned int T   = l & ~63u;
    unsigned int loc = l & 63;
    unsigned int sg = loc >> 5, w = loc & 31;
    unsigned int hh = w >> 4, g0 = (w >> 2) & 3;         // w in {0,8,16,24} -> g0 in {0,2}
    const float* src = M + (size_t)row * SK + T + sg * 32 + hh * 4;
    float4 a = *(const float4*)(src + g0 * 8);
    float4 b = *(const float4*)(src + (g0 + 1) * 8);
    bf8 o;
    o[0] = (short)f2bf(a.x * CL2E); o[1] = (short)f2bf(a.y * CL2E);
    o[2] = (short)f2bf(a.z * CL2E); o[3] = (short)f2bf(a.w * CL2E);
    o[4] = (short)f2bf(b.x * CL2E); o[5] = (short)f2bf(b.y * CL2E);
    o[6] = (short)f2bf(b.z * CL2E); o[7] = (short)f2bf(b.w * CL2E);
    *(bf8*)(Mb + (size_t)row * SK + l) = o;
}

// ---------------- main fused attention ----------------
// 4 waves = 2 q-groups (64 q) x 2 s-halves (32 s). QK^T split per q-tile to keep
// unified VGPR+AGPR <= 256 (R2 spilled at ~280 -> 505MB fetch / 167MB write).
__global__ __launch_bounds__(256, 2) void fattn_kernel(
    const float* __restrict__ Q, const unsigned short* __restrict__ Kb,
    const unsigned short* __restrict__ VTb, const unsigned short* __restrict__ Mb,
    float* __restrict__ O)
{
    __shared__ __align__(1024) unsigned char smem[65536];
    unsigned char* KB = smem;               // 2 x 16KB K tiles [s=64][256B swz]
    unsigned char* VB = smem + 32768;       // 2 x 16KB V tiles [d=128][128B swz]

    const int tid  = threadIdx.x;
    const int wave = tid >> 6;
    const int lane = tid & 63;
    const int l32  = lane & 31;
    const int hh   = lane >> 5;
    const int qg   = wave >> 1;             // q-group (64 rows)
    const int sg   = wave & 1;              // s-half (32 cols)

    // XCD swizzle: 64 consecutive logical blocks (= 1 kv head) per XCD
    const int bx = ((int)blockIdx.x & 7) * 64 + ((int)blockIdx.x >> 3);
    const int h  = bx >> 4;
    const int lt = bx & 15;
    const int q0 = lt * BM;
    const int kv = h >> 2;

    const float* Qh = Q + (size_t)h * LQ * DH;
    const unsigned char* Kg = (const unsigned char*)(Kb  + (size_t)kv * SK * DH);
    const unsigned char* Vg = (const unsigned char*)(VTb + (size_t)kv * SK * DH);

    const int qrow0 = q0 + qg * 64 + l32;
    const unsigned short* Mq0 = Mb + (size_t)qrow0 * SK + sg * 32 + hh * 16;
    const unsigned short* Mq1 = Mq0 + (size_t)32 * SK;

    // ---- Q preload as B-fragments: n=q, k=d = ks*16 + hh*8 + j ----
    bf8 bQ[2][8];
    #pragma unroll
    for (int qt = 0; qt < 2; ++qt) {
        const float* qp = Qh + (size_t)(qrow0 + qt * 32) * DH + hh * 8;
        #pragma unroll
        for (int ks = 0; ks < 8; ++ks) {
            float4 a = *(const float4*)(qp + ks * 16);
            float4 b = *(const float4*)(qp + ks * 16 + 4);
            bf8 o;
            o[0] = (short)f2bf(a.x); o[1] = (short)f2bf(a.y);
            o[2] = (short)f2bf(a.z); o[3] = (short)f2bf(a.w);
            o[4] = (short)f2bf(b.x); o[5] = (short)f2bf(b.y);
            o[6] = (short)f2bf(b.z); o[7] = (short)f2bf(b.w);
            bQ[qt][ks] = o;
        }
    }

    // LDS read byte-offset bases; per-read addr = base ^ (ks<<5) (bits disjoint)
    const int krowz = (sg * 32 + l32) * 256 + ((hh * 16) ^ ((l32 & 15) << 4));
    const int vrowz = l32 * 128 + ((sg * 64 + hh * 16) ^ ((l32 & 7) << 4));

    const int stoff = wave * 4096 + lane * 16;   // staging: 4KB K + 4KB V per wave

    f16v accO[4][2];
    #pragma unroll
    for (int dt = 0; dt < 4; ++dt)
        #pragma unroll
        for (int qt = 0; qt < 2; ++qt)
            #pragma unroll
            for (int r = 0; r < 16; ++r) accO[dt][qt][r] = 0.f;
    float lp0 = 0.f, lp1 = 0.f;

    // prologue: stage tile 0 into buffer 0
    #pragma unroll
    for (int c = 0; c < 4; ++c) GLOAD_LDS16(Kg + stoff + c * 1024, KB + stoff + c * 1024);
    #pragma unroll
    for (int c = 0; c < 4; ++c) GLOAD_LDS16(Vg + stoff + c * 1024, VB + stoff + c * 1024);

    for (int t = 0; t < NT; ++t) {
        const int cur = t & 1;

        // ---- mask loads for tile t (bf16 packed, pre-scaled): 4 x b128 ----
        const unsigned short* mp0 = Mq0 + t * 64;
        const unsigned short* mp1 = Mq1 + t * 64;
        u32x4 mA0 = *(const u32x4*)(mp0);
        u32x4 mB0 = *(const u32x4*)(mp0 + 8);
        u32x4 mA1 = *(const u32x4*)(mp1);
        u32x4 mB1 = *(const u32x4*)(mp1 + 8);
        __builtin_amdgcn_sched_barrier(0);

        // ---- stage tile t+1 (wrap on last iter keeps vmcnt bookkeeping uniform) ----
        {
            const int tn = (t + 1) & (NT - 1);
            const unsigned char* ksrc = Kg + (size_t)tn * 16384 + stoff;
            const unsigned char* vsrc = Vg + (size_t)tn * 16384 + stoff;
            unsigned char* kdst = KB + (cur ^ 1) * 16384 + stoff;
            unsigned char* vdst = VB + (cur ^ 1) * 16384 + stoff;
            #pragma unroll
            for (int c = 0; c < 4; ++c) GLOAD_LDS16(ksrc + c * 1024, kdst + c * 1024);
            #pragma unroll
            for (int c = 0; c < 4; ++c) GLOAD_LDS16(vsrc + c * 1024, vdst + c * 1024);
        }
        __builtin_amdgcn_sched_barrier(0);
        // outstanding: stage_t(8) + mask_t(4) + stage_{t+1}(8) -> drain stage_t only
        asm volatile("s_waitcnt vmcnt(12)" ::: "memory");
        __builtin_amdgcn_s_barrier();
        asm volatile("" ::: "memory");

        const unsigned char* kb = KB + cur * 16384;
        const unsigned char* vb = VB + cur * 16384;

        // ---- qt0: S^T = K*Q^T, then softmax into pk0 ----
        unsigned int pk0[8], pk1[8];
        {
            f16v s;
            #pragma unroll
            for (int r = 0; r < 16; ++r) s[r] = 0.f;
            __builtin_amdgcn_s_setprio(1);
            #pragma unroll
            for (int ks = 0; ks < 8; ++ks) {
                bf8 aK = *(const bf8*)(kb + (krowz ^ (ks << 5)));
                s = __builtin_amdgcn_mfma_f32_32x32x16_bf16(aK, bQ[0][ks], s, 0, 0, 0);
            }
            __builtin_amdgcn_s_setprio(0);
            #pragma unroll
            for (int g = 0; g < 4; ++g) {
                unsigned int u0 = (g < 2) ? mA0[g * 2 + 0] : mB0[(g - 2) * 2 + 0];
                unsigned int u1 = (g < 2) ? mA0[g * 2 + 1] : mB0[(g - 2) * 2 + 1];
                float e0 = EXP2F(fmaf(s[g*4+0], CL2E, bflo(u0)));
                float e1 = EXP2F(fmaf(s[g*4+1], CL2E, bfhi(u0)));
                float e2 = EXP2F(fmaf(s[g*4+2], CL2E, bflo(u1)));
                float e3 = EXP2F(fmaf(s[g*4+3], CL2E, bfhi(u1)));
                lp0 += (e0 + e1) + (e2 + e3);
                pk0[g*2+0] = cvtpk_bf16(e0, e1);
                pk0[g*2+1] = cvtpk_bf16(e2, e3);
            }
        }
        // ---- qt1 ----
        {
            f16v s;
            #pragma unroll
            for (int r = 0; r < 16; ++r) s[r] = 0.f;
            __builtin_amdgcn_s_setprio(1);
            #pragma unroll
            for (int ks = 0; ks < 8; ++ks) {
                bf8 aK = *(const bf8*)(kb + (krowz ^ (ks << 5)));
                s = __builtin_amdgcn_mfma_f32_32x32x16_bf16(aK, bQ[1][ks], s, 0, 0, 0);
            }
            __builtin_amdgcn_s_setprio(0);
            #pragma unroll
            for (int g = 0; g < 4; ++g) {
                unsigned int u0 = (g < 2) ? mA1[g * 2 + 0] : mB1[(g - 2) * 2 + 0];
                unsigned int u1 = (g < 2) ? mA1[g * 2 + 1] : mB1[(g - 2) * 2 + 1];
                float e0 = EXP2F(fmaf(s[g*4+0], CL2E, bflo(u0)));
                float e1 = EXP2F(fmaf(s[g*4+1], CL2E, bfhi(u0)));
                float e2 = EXP2F(fmaf(s[g*4+2], CL2E, bflo(u1)));
                float e3 = EXP2F(fmaf(s[g*4+3], CL2E, bfhi(u1)));
                lp1 += (e0 + e1) + (e2 + e3);
                pk1[g*2+0] = cvtpk_bf16(e0, e1);
                pk1[g*2+1] = cvtpk_bf16(e2, e3);
            }
        }

        // half-wave exchange via v_permlane32_swap_b32 (newA={A_lo,B_lo}, newB={A_hi,B_hi}):
        // w0 = half0 pk[2G], w1 = half0 pk[2G+1], w2 = half1 pk[2G], w3 = half1 pk[2G+1]
        bf8 bP0[2], bP1[2];
        #pragma unroll
        for (int ks = 0; ks < 2; ++ks) {
            unsigned int a0 = pk0[4*ks+0], b0 = pk0[4*ks+2];
            unsigned int a1 = pk0[4*ks+1], b1 = pk0[4*ks+3];
            asm volatile("v_permlane32_swap_b32 %0, %1" : "+v"(a0), "+v"(b0));
            asm volatile("v_permlane32_swap_b32 %0, %1" : "+v"(a1), "+v"(b1));
            u32x4 w; w[0] = a0; w[1] = a1; w[2] = b0; w[3] = b1;
            bP0[ks] = __builtin_bit_cast(bf8, w);
            unsigned int c0 = pk1[4*ks+0], d0 = pk1[4*ks+2];
            unsigned int c1 = pk1[4*ks+1], d1 = pk1[4*ks+3];
            asm volatile("v_permlane32_swap_b32 %0, %1" : "+v"(c0), "+v"(d0));
            asm volatile("v_permlane32_swap_b32 %0, %1" : "+v"(c1), "+v"(d1));
            u32x4 w2; w2[0] = c0; w2[1] = c1; w2[2] = d0; w2[3] = d1;
            bP1[ks] = __builtin_bit_cast(bf8, w2);
        }

        // ---- O^T += V^T * P^T over this wave's 32-s half (k-split; reduced at end) ----
        __builtin_amdgcn_s_setprio(1);
        #pragma unroll
        for (int dt = 0; dt < 4; ++dt) {
            #pragma unroll
            for (int ks = 0; ks < 2; ++ks) {
                bf8 aV = *(const bf8*)(vb + dt * 4096 + (vrowz ^ (ks << 5)));
                accO[dt][0] = __builtin_amdgcn_mfma_f32_32x32x16_bf16(aV, bP0[ks], accO[dt][0], 0, 0, 0);
                accO[dt][1] = __builtin_amdgcn_mfma_f32_32x32x16_bf16(aV, bP1[ks], accO[dt][1], 0, 0, 0);
            }
        }
        __builtin_amdgcn_s_setprio(0);
        asm volatile("" ::: "memory");
        __builtin_amdgcn_s_barrier();
        asm volatile("" ::: "memory");
    }

    // ---- epilogue: combine the two s-halves via LDS (2 rounds of 32KB) ----
    asm volatile("s_waitcnt vmcnt(0)" ::: "memory");   // drain wrap-stage before reuse
    __builtin_amdgcn_s_barrier();
    asm volatile("" ::: "memory");
    float* xs  = (float*)smem;              // 32KB per round: [qg][dt][r][lane]
    float* lsc = (float*)(smem + 32768);    // 2KB lpart exchange
    const int pw = qg * 2 + (sg ^ 1);       // partner wave id
    lsc[(wave * 2 + 0) * 64 + lane] = lp0;
    lsc[(wave * 2 + 1) * 64 + lane] = lp1;
    float lq[2];
    float* Op0 = O + (size_t)h * LQ * DH + (size_t)qrow0 * DH;
    #pragma unroll
    for (int qt = 0; qt < 2; ++qt) {
        #pragma unroll
        for (int i = 0; i < 2; ++i) {           // export partner-owned d-tiles
            const int dt = (sg ^ 1) * 2 + i;
            #pragma unroll
            for (int r = 0; r < 16; ++r)
                xs[((qg * 4 + dt) * 16 + r) * 64 + lane] = accO[dt][qt][r];
        }
        asm volatile("" ::: "memory");
        __builtin_amdgcn_s_barrier();
        asm volatile("" ::: "memory");
        if (qt == 0) {
            lq[0] = lp0 + lsc[(pw * 2 + 0) * 64 + lane];
            lq[1] = lp1 + lsc[(pw * 2 + 1) * 64 + lane];
            lq[0] += __shfl_xor(lq[0], 32);
            lq[1] += __shfl_xor(lq[1], 32);
        }
        const float inv = 1.0f / lq[qt];
        float* Op = Op0 + (size_t)qt * 32 * DH;
        #pragma unroll
        for (int i = 0; i < 2; ++i) {           // own d-tiles: add partner partial, store
            const int dt = sg * 2 + i;
            #pragma unroll
            for (int g = 0; g < 4; ++g) {
                float4 o;
                o.x = (accO[dt][qt][g*4+0] + xs[((qg*4+dt)*16 + g*4+0)*64 + lane]) * inv;
                o.y = (accO[dt][qt][g*4+1] + xs[((qg*4+dt)*16 + g*4+1)*64 + lane]) * inv;
                o.z = (accO[dt][qt][g*4+2] + xs[((qg*4+dt)*16 + g*4+2)*64 + lane]) * inv;
                o.w = (accO[dt][qt][g*4+3] + xs[((qg*4+dt)*16 + g*4+3)*64 + lane]) * inv;
                *(float4*)(Op + dt * 32 + g * 8 + hh * 4) = o;
            }
        }
        if (qt == 0) {
            asm volatile("" ::: "memory");
            __builtin_amdgcn_s_barrier();       // protect xs before qt=1 export
            asm volatile("" ::: "memory");
        }
    }
}

extern "C" void kernel_launch(void* const* d_in, const int* in_sizes, int n_in,
                              void* d_out, int out_size, void* d_ws, size_t ws_size,
                              hipStream_t stream) {
    const float* Q = (const float*)d_in[0];   // [1,32,2048,128]
    const float* K = (const float*)d_in[1];   // [1,8,2048,128]
    const float* V = (const float*)d_in[2];   // [1,8,2048,128]
    const float* M = (const float*)d_in[3];   // [1,1,2048,2048]
    float* O = (float*)d_out;

    // workspace: Kb bf16 [8*2048*128], VTb bf16 [8*128*2048], Mb bf16 [2048*2048]
    unsigned short* Kb  = (unsigned short*)d_ws;
    unsigned short* VTb = Kb + (size_t)NKV * SK * DH;
    unsigned short* Mb  = VTb + (size_t)NKV * DH * SK;

    convert_k_kernel<<<dim3((NKV * SK * 16) / 256), 256, 0, stream>>>(K, Kb);
    transpose_v_kernel<<<dim3(NKV * (SK / 64)), 256, 0, stream>>>(V, VTb);
    convert_m_kernel<<<dim3((LQ * (SK / 8)) / 256), 256, 0, stream>>>(M, Mb);

    dim3 grid(NH * (LQ / BM));                // 512 blocks = 2/CU
    fattn_kernel<<<grid, 256, 0, stream>>>(Q, Kb, VTb, Mb, O);
}

// Round 5
// 185.138 us; speedup vs baseline: 2.2154x; 1.9248x over previous
//
#include <hip/hip_runtime.h>

// Problem constants
#define NH   32      // query heads
#define NKV  8       // kv heads
#define LQ   2048    // query length
#define SK   2048    // key length
#define DH   128     // head dim
#define BM   128     // q rows per block (4 waves x 32 q)
#define BN   64      // s columns per iteration
#define NT   (SK / BN)   // 32 k-tiles
#define VSTRIDE 72   // prepass transpose LDS stride (shorts)

typedef __attribute__((ext_vector_type(8)))  short bf8;
typedef __attribute__((ext_vector_type(16))) float f16v;
typedef __attribute__((ext_vector_type(4)))  unsigned int u32x4;

#define CL2E 0.12754308753f   // (1/sqrt(128)) * log2(e)

#if __has_builtin(__builtin_amdgcn_exp2f)
#define EXP2F(x) __builtin_amdgcn_exp2f(x)
#else
#define EXP2F(x) exp2f(x)
#endif

// fp32 -> bf16 round-to-nearest-even (finite inputs)
__device__ __forceinline__ unsigned short f2bf(float f) {
    unsigned int u = __builtin_bit_cast(unsigned int, f);
    u = (u + 0x7FFFu + ((u >> 16) & 1u)) >> 16;
    return (unsigned short)u;
}

__device__ __forceinline__ unsigned int cvtpk_bf16(float lo, float hi) {
    unsigned int r;
    asm("v_cvt_pk_bf16_f32 %0, %1, %2" : "=v"(r) : "v"(lo), "v"(hi));
    return r;
}

__device__ __forceinline__ float bflo(unsigned int u) {
    return __builtin_bit_cast(float, u << 16);
}
__device__ __forceinline__ float bfhi(unsigned int u) {
    return __builtin_bit_cast(float, u & 0xFFFF0000u);
}

// offset argument must be a LITERAL 0; fold offsets into both pointers.
#define GLOAD_LDS16(g, l)                                                      \
    __builtin_amdgcn_global_load_lds(                                          \
        (const __attribute__((address_space(1))) void*)(g),                    \
        (__attribute__((address_space(3))) void*)(l), 16, 0, 0)

// ---------------- pre-pass 1: K fp32 -> bf16, chunk-swizzled rows ----------------
// Kb[kv][s][p] (16B chunks p=0..15) holds source d-chunk c = p ^ (s&15): linear
// global->LDS DMA of a 64-row tile yields an XOR-swizzled LDS tile.
__global__ __launch_bounds__(256) void convert_k_kernel(
    const float* __restrict__ K, unsigned short* __restrict__ Kb)
{
    unsigned int cid = blockIdx.x * 256 + threadIdx.x;   // one 16B chunk per thread
    unsigned int p   = cid & 15;
    unsigned int row = cid >> 4;            // kv*2048 + s
    unsigned int s   = row & (SK - 1);
    unsigned int c   = p ^ (s & 15);
    const float* src = K + (size_t)row * DH + c * 8;
    float4 a = *(const float4*)(src);
    float4 b = *(const float4*)(src + 4);
    bf8 o;
    o[0] = (short)f2bf(a.x); o[1] = (short)f2bf(a.y);
    o[2] = (short)f2bf(a.z); o[3] = (short)f2bf(a.w);
    o[4] = (short)f2bf(b.x); o[5] = (short)f2bf(b.y);
    o[6] = (short)f2bf(b.z); o[7] = (short)f2bf(b.w);
    *(bf8*)(Kb + (size_t)row * DH + p * 8) = o;
}

// ---------------- pre-pass 2: V -> V^T bf16, TILE-blocked + chunk-swizzled ----------------
// VTb layout: [kv][tile t (64 s)][d=0..127][p=0..7] 16B chunks; chunk p of row d
// holds s-chunk c = p ^ (d&7). Each tile is 16KB contiguous -> linear DMA staging.
__global__ __launch_bounds__(256) void transpose_v_kernel(
    const float* __restrict__ V, unsigned short* __restrict__ VTb)
{
    __shared__ __align__(16) unsigned short Vl[DH * VSTRIDE];
    const int tid = threadIdx.x;
    const int kv  = blockIdx.x >> 5;          // 32 s-tiles per kv head
    const int t   = blockIdx.x & 31;
    const int s0  = t * 64;
    const float* Vh = V + (size_t)kv * SK * DH;

    #pragma unroll
    for (int i = 0; i < 8; ++i) {
        int idx = tid * 4 + i * 1024;
        int s = idx >> 7, d = idx & 127;
        const float4 v4 = *(const float4*)(Vh + (size_t)(s0 + s) * DH + d);
        Vl[(d + 0) * VSTRIDE + s] = f2bf(v4.x);
        Vl[(d + 1) * VSTRIDE + s] = f2bf(v4.y);
        Vl[(d + 2) * VSTRIDE + s] = f2bf(v4.z);
        Vl[(d + 3) * VSTRIDE + s] = f2bf(v4.w);
    }
    __syncthreads();
    unsigned short* out = VTb + (size_t)(kv * 32 + t) * (DH * 64);
    #pragma unroll
    for (int i = 0; i < 4; ++i) {
        int c = tid + i * 256;                // 1024 chunks of 8 shorts
        int d = c >> 3, p = c & 7;
        int sc = (p ^ (d & 7)) * 8;
        *(bf8*)(out + d * 64 + p * 8) = *(const bf8*)(Vl + d * VSTRIDE + sc);
    }
}

// ---------------- pre-pass 3: mask fp32 -> bf16, pre-scaled by scale*log2e ----------------
// Column-permuted within each 64-col tile: local c' = mt*32 + hh*16 + g*4 + j holds
// source col mt*32 + g*8 + hh*4 + j (matches 32x32 MFMA D-layout row = j + 8g + 4hh).
__global__ __launch_bounds__(256) void convert_m_kernel(
    const float* __restrict__ M, unsigned short* __restrict__ Mb)
{
    unsigned int cid = blockIdx.x * 256 + threadIdx.x;   // one 8-short output chunk
    unsigned int row = cid >> 8;                         // 256 chunks per row
    unsigned int l   = (cid & 255) * 8;                  // permuted col index
    unsigned int T   = l & ~63u;
    unsigned int loc = l & 63;
    unsigned int mt = loc >> 5, w = loc & 31;
    unsigned int hh = w >> 4, g0 = (w >> 2) & 3;         // w in {0,8,16,24} -> g0 in {0,2}
    const float* src = M + (size_t)row * SK + T + mt * 32 + hh * 4;
    float4 a = *(const float4*)(src + g0 * 8);
    float4 b = *(const float4*)(src + (g0 + 1) * 8);
    bf8 o;
    o[0] = (short)f2bf(a.x * CL2E); o[1] = (short)f2bf(a.y * CL2E);
    o[2] = (short)f2bf(a.z * CL2E); o[3] = (short)f2bf(a.w * CL2E);
    o[4] = (short)f2bf(b.x * CL2E); o[5] = (short)f2bf(b.y * CL2E);
    o[6] = (short)f2bf(b.z * CL2E); o[7] = (short)f2bf(b.w * CL2E);
    *(bf8*)(Mb + (size_t)row * SK + l) = o;
}

// ---------------- main fused attention ----------------
// 4 waves = 4 q-tiles of 32 rows (no s-split). Per wave per 64-s tile:
//   S^T = K*Q^T over mt=0,1 (16 MFMA), softmax in-register (permlane P-pack),
//   O^T += V^T*P^T over 4 ks (16 MFMA). Waves own disjoint O rows -> no epilogue
//   reduction. Register plan: accO 64 + bQ 32 + pk 16 + masks 16 + s 16 ~= 150,
//   well under the 256 unified cap (R2/R4 spilled at ~280 with the s-split plan).
__global__ __launch_bounds__(256, 2) void fattn_kernel(
    const float* __restrict__ Q, const unsigned short* __restrict__ Kb,
    const unsigned short* __restrict__ VTb, const unsigned short* __restrict__ Mb,
    float* __restrict__ O)
{
    __shared__ __align__(1024) unsigned char smem[65536];
    unsigned char* KB = smem;               // 2 x 16KB K tiles [s=64][256B swz]
    unsigned char* VB = smem + 32768;       // 2 x 16KB V tiles [d=128][128B swz]

    const int tid  = threadIdx.x;
    const int wave = tid >> 6;              // q-tile index
    const int lane = tid & 63;
    const int l32  = lane & 31;
    const int hh   = lane >> 5;

    // XCD swizzle: 64 consecutive logical blocks (= 1 kv head) per XCD
    const int bx = ((int)blockIdx.x & 7) * 64 + ((int)blockIdx.x >> 3);
    const int h  = bx >> 4;
    const int lt = bx & 15;
    const int q0 = lt * BM;
    const int kv = h >> 2;

    const float* Qh = Q + (size_t)h * LQ * DH;
    const unsigned char* Kg = (const unsigned char*)(Kb  + (size_t)kv * SK * DH);
    const unsigned char* Vg = (const unsigned char*)(VTb + (size_t)kv * SK * DH);

    const int qrow = q0 + wave * 32 + l32;
    const unsigned short* Mq = Mb + (size_t)qrow * SK + hh * 16;

    // ---- Q preload as B-fragments: n=q, k=d = ks*16 + hh*8 + j ----
    bf8 bQ[8];
    {
        const float* qp = Qh + (size_t)qrow * DH + hh * 8;
        #pragma unroll
        for (int ks = 0; ks < 8; ++ks) {
            float4 a = *(const float4*)(qp + ks * 16);
            float4 b = *(const float4*)(qp + ks * 16 + 4);
            bf8 o;
            o[0] = (short)f2bf(a.x); o[1] = (short)f2bf(a.y);
            o[2] = (short)f2bf(a.z); o[3] = (short)f2bf(a.w);
            o[4] = (short)f2bf(b.x); o[5] = (short)f2bf(b.y);
            o[6] = (short)f2bf(b.z); o[7] = (short)f2bf(b.w);
            bQ[ks] = o;
        }
    }

    // LDS read byte-offset bases; per-read addr = base ^ (ks<<5) (XOR bits disjoint
    // from the non-swizzle part of the base)
    const int krow0 = l32 * 256 + ((hh * 16) ^ ((l32 & 15) << 4));   // + mt*8192
    const int vrowz = l32 * 128 + ((hh * 16) ^ ((l32 & 7) << 4));    // + dt*4096

    const int stoff = wave * 4096 + lane * 16;   // staging: 4KB K + 4KB V per wave

    f16v accO[4];     // O^T tiles over d (4 x 32); col=q, row=d
    #pragma unroll
    for (int dt = 0; dt < 4; ++dt)
        #pragma unroll
        for (int r = 0; r < 16; ++r) accO[dt][r] = 0.f;
    float lpart = 0.f;

    // prologue: stage tile 0 into buffer 0
    #pragma unroll
    for (int c = 0; c < 4; ++c) GLOAD_LDS16(Kg + stoff + c * 1024, KB + stoff + c * 1024);
    #pragma unroll
    for (int c = 0; c < 4; ++c) GLOAD_LDS16(Vg + stoff + c * 1024, VB + stoff + c * 1024);

    for (int t = 0; t < NT; ++t) {
        const int cur = t & 1;

        // ---- mask loads for tile t (bf16 packed, pre-scaled): 4 x b128 ----
        const unsigned short* mp = Mq + t * 64;
        u32x4 mA0 = *(const u32x4*)(mp);
        u32x4 mB0 = *(const u32x4*)(mp + 8);
        u32x4 mA1 = *(const u32x4*)(mp + 32);
        u32x4 mB1 = *(const u32x4*)(mp + 40);
        __builtin_amdgcn_sched_barrier(0);

        // ---- stage tile t+1 (wrap on last iter keeps vmcnt bookkeeping uniform) ----
        {
            const int tn = (t + 1) & (NT - 1);
            const unsigned char* ksrc = Kg + (size_t)tn * 16384 + stoff;
            const unsigned char* vsrc = Vg + (size_t)tn * 16384 + stoff;
            unsigned char* kdst = KB + (cur ^ 1) * 16384 + stoff;
            unsigned char* vdst = VB + (cur ^ 1) * 16384 + stoff;
            #pragma unroll
            for (int c = 0; c < 4; ++c) GLOAD_LDS16(ksrc + c * 1024, kdst + c * 1024);
            #pragma unroll
            for (int c = 0; c < 4; ++c) GLOAD_LDS16(vsrc + c * 1024, vdst + c * 1024);
        }
        __builtin_amdgcn_sched_barrier(0);
        // outstanding: stage_t(8) + mask_t(4) + stage_{t+1}(8) -> drain stage_t only
        asm volatile("s_waitcnt vmcnt(12)" ::: "memory");
        __builtin_amdgcn_s_barrier();
        asm volatile("" ::: "memory");

        const unsigned char* kb = KB + cur * 16384;
        const unsigned char* vb = VB + cur * 16384;

        // ---- per mt (32 s rows): S^T = K*Q^T, softmax into pk[mt] ----
        unsigned int pk0[8], pk1[8];
        #pragma unroll
        for (int mt = 0; mt < 2; ++mt) {
            f16v s;
            #pragma unroll
            for (int r = 0; r < 16; ++r) s[r] = 0.f;
            __builtin_amdgcn_s_setprio(1);
            #pragma unroll
            for (int ks = 0; ks < 8; ++ks) {
                bf8 aK = *(const bf8*)(kb + mt * 8192 + (krow0 ^ (ks << 5)));
                s = __builtin_amdgcn_mfma_f32_32x32x16_bf16(aK, bQ[ks], s, 0, 0, 0);
            }
            __builtin_amdgcn_s_setprio(0);
            const u32x4 mA = mt ? mA1 : mA0;
            const u32x4 mB = mt ? mB1 : mB0;
            unsigned int* pk = mt ? pk1 : pk0;
            #pragma unroll
            for (int g = 0; g < 4; ++g) {
                unsigned int u0 = (g < 2) ? mA[g * 2 + 0] : mB[(g - 2) * 2 + 0];
                unsigned int u1 = (g < 2) ? mA[g * 2 + 1] : mB[(g - 2) * 2 + 1];
                float e0 = EXP2F(fmaf(s[g*4+0], CL2E, bflo(u0)));
                float e1 = EXP2F(fmaf(s[g*4+1], CL2E, bfhi(u0)));
                float e2 = EXP2F(fmaf(s[g*4+2], CL2E, bflo(u1)));
                float e3 = EXP2F(fmaf(s[g*4+3], CL2E, bfhi(u1)));
                lpart += (e0 + e1) + (e2 + e3);
                pk[g*2+0] = cvtpk_bf16(e0, e1);
                pk[g*2+1] = cvtpk_bf16(e2, e3);
            }
        }

        // half-wave exchange via v_permlane32_swap_b32 (newA={A_lo,B_lo}, newB={A_hi,B_hi}):
        // bP[ks] (k = s = ks*16 + hh*8 + 0..7): mt = ks>>1, kk = ks&1, g = kk*2 + hh:
        // w0 = half0 pk[mt][2g], w1 = half0 pk[mt][2g+1], w2 = half1 pk[mt][2g],
        // w3 = half1 pk[mt][2g+1] -> swap(pk[mt][kk*4], pk[mt][kk*4+2]) gives w0/w2,
        // swap(pk[mt][kk*4+1], pk[mt][kk*4+3]) gives w1/w3 (same pattern verified in R4).
        bf8 bP[4];
        #pragma unroll
        for (int ks = 0; ks < 4; ++ks) {
            unsigned int* pk = (ks >> 1) ? pk1 : pk0;
            const int kk = ks & 1;
            unsigned int a0 = pk[kk*4+0], b0 = pk[kk*4+2];
            unsigned int a1 = pk[kk*4+1], b1 = pk[kk*4+3];
            asm volatile("v_permlane32_swap_b32 %0, %1" : "+v"(a0), "+v"(b0));
            asm volatile("v_permlane32_swap_b32 %0, %1" : "+v"(a1), "+v"(b1));
            u32x4 w; w[0] = a0; w[1] = a1; w[2] = b0; w[3] = b1;
            bP[ks] = __builtin_bit_cast(bf8, w);
        }

        // ---- O^T += V^T * P^T over all 64 s (4 k-steps) ----
        __builtin_amdgcn_s_setprio(1);
        #pragma unroll
        for (int dt = 0; dt < 4; ++dt) {
            #pragma unroll
            for (int ks = 0; ks < 4; ++ks) {
                bf8 aV = *(const bf8*)(vb + dt * 4096 + (vrowz ^ (ks << 5)));
                accO[dt] = __builtin_amdgcn_mfma_f32_32x32x16_bf16(aV, bP[ks], accO[dt], 0, 0, 0);
            }
        }
        __builtin_amdgcn_s_setprio(0);
        asm volatile("" ::: "memory");
        __builtin_amdgcn_s_barrier();
        asm volatile("" ::: "memory");
    }

    // ---- epilogue: waves own disjoint O rows -> no reduction ----
    asm volatile("s_waitcnt vmcnt(0)" ::: "memory");   // drain wrap-stage
    float l = lpart + __shfl_xor(lpart, 32);
    float inv = 1.0f / l;
    float* Op = O + (size_t)h * LQ * DH + (size_t)qrow * DH;
    #pragma unroll
    for (int dt = 0; dt < 4; ++dt) {
        #pragma unroll
        for (int g = 0; g < 4; ++g) {
            int d = dt * 32 + g * 8 + hh * 4;
            float4 o;
            o.x = accO[dt][g * 4 + 0] * inv;
            o.y = accO[dt][g * 4 + 1] * inv;
            o.z = accO[dt][g * 4 + 2] * inv;
            o.w = accO[dt][g * 4 + 3] * inv;
            *(float4*)(Op + d) = o;
        }
    }
}

extern "C" void kernel_launch(void* const* d_in, const int* in_sizes, int n_in,
                              void* d_out, int out_size, void* d_ws, size_t ws_size,
                              hipStream_t stream) {
    const float* Q = (const float*)d_in[0];   // [1,32,2048,128]
    const float* K = (const float*)d_in[1];   // [1,8,2048,128]
    const float* V = (const float*)d_in[2];   // [1,8,2048,128]
    const float* M = (const float*)d_in[3];   // [1,1,2048,2048]
    float* O = (float*)d_out;

    // workspace: Kb bf16 [8*2048*128], VTb bf16 [8*128*2048], Mb bf16 [2048*2048]
    unsigned short* Kb  = (unsigned short*)d_ws;
    unsigned short* VTb = Kb + (size_t)NKV * SK * DH;
    unsigned short* Mb  = VTb + (size_t)NKV * DH * SK;

    convert_k_kernel<<<dim3((NKV * SK * 16) / 256), 256, 0, stream>>>(K, Kb);
    transpose_v_kernel<<<dim3(NKV * (SK / 64)), 256, 0, stream>>>(V, VTb);
    convert_m_kernel<<<dim3((LQ * (SK / 8)) / 256), 256, 0, stream>>>(M, Mb);

    dim3 grid(NH * (LQ / BM));                // 512 blocks = 2/CU
    fattn_kernel<<<grid, 256, 0, stream>>>(Q, Kb, VTb, Mb, O);
}